// Round 9
// baseline (128.949 us; speedup 1.0000x reference)
//
#include <hip/hip_runtime.h>

#define N_TOTAL 32768
#define D_DIM   512
#define C_DIM   64
#define M_DIM   128
#define NODES_  15
#define ROWS_B  128         // rows per block -> grid = 256 = 1 block/CU
#define NSUB    8           // 8 subtiles x 16 rows

typedef unsigned short u16;
typedef unsigned int   u32;
typedef unsigned long long u64;
typedef unsigned char  u8;
typedef float  f32x4   __attribute__((ext_vector_type(4)));
typedef short  short8v __attribute__((ext_vector_type(8)));

#define WAIT_VM(N) asm volatile("s_waitcnt vmcnt(" #N ")" ::: "memory")

__device__ __forceinline__ u32 f2bf_bits(float f) {
    u32 u = __float_as_uint(f);
    return (u + 0x7FFFu + ((u >> 16) & 1u)) >> 16;   // RNE
}

// raw barrier that does NOT drain vmcnt (keeps HBM staging in flight);
// lgkmcnt(0) makes prior ds_writes visible, trailing fence stops hoisting.
__device__ __forceinline__ void lds_barrier() {
    asm volatile("s_waitcnt lgkmcnt(0)" ::: "memory");
    __builtin_amdgcn_s_barrier();
    asm volatile("" ::: "memory");
}

// coalesced global -> LDS direct copy, 16 B/lane (wave-uniform LDS base)
__device__ __forceinline__ void gload_lds16(const float* g, float* l) {
    __builtin_amdgcn_global_load_lds(
        (const __attribute__((address_space(1))) void*)g,
        (__attribute__((address_space(3))) void*)l, 16, 0, 0);
}

// ---------------------------------------------------------------------------
// Kernel 1 (unchanged, r4-verified): Lbf = L in MFMA-B-fragment order, bf16.
// Fragment (ct, ch): lane holds B[k][n], n = ct*16 + (lane&15),
// k = ch*32 + (lane>>4)*8 + i. Layout [ct][ch][lane][8]. 256 KB, L2-resident.
// ---------------------------------------------------------------------------
__global__ __launch_bounds__(256) void build_lbf(
    const float* __restrict__ L, u16* __restrict__ Lbf)
{
    int idx  = blockIdx.x * 256 + threadIdx.x;   // 16384 threads = 64 blocks
    int lane = idx & 63;
    int ch   = (idx >> 6) & 31;
    int ct   = idx >> 11;                        // 0..7
    int m  = ct * 16 + (lane & 15);
    int k0 = ch * 32 + ((lane >> 4) * 8);
    const float* src = L + (size_t)m * 1024 + k0;
    float4 a = *(const float4*)(src);
    float4 b = *(const float4*)(src + 4);
    u32 w0 = f2bf_bits(a.x) | (f2bf_bits(a.y) << 16);
    u32 w1 = f2bf_bits(a.z) | (f2bf_bits(a.w) << 16);
    u32 w2 = f2bf_bits(b.x) | (f2bf_bits(b.y) << 16);
    u32 w3 = f2bf_bits(b.z) | (f2bf_bits(b.w) << 16);
    *(uint4*)(Lbf + (size_t)idx * 8) = make_uint4(w0, w1, w2, w3);
}

// ---------------------------------------------------------------------------
// Kernel 2 (pipelined megakernel): 128 rows/block, 8 waves, grid 256.
// Wave wv owns col-tile ct=wv; its 32 B-fragments live in REGISTERS
// (32 x uint4, loaded once at prologue) -> gemm is register/LDS-only.
// 8 subtiles of 16 rows, 2-deep staged pipeline:
//   iter t: gemm+store(t) | issue stage(t+2) | WAIT_VM(4) | descend(t+1)
//           | write codes | lds_barrier (raw: staging stays in flight).
// Per-wave-private sI regions (rows 2wv,2wv+1 of each subtile) -> no
// cross-wave hazard on sI; sC double-buffered, only cross-wave data.
// Verified math carried over: descent (r2), one-hot A synth + Lbf fragment
// layout (r4), C/D col=lane&15 row=(lane>>4)*4+j (m89). h==0 -> bit 0 ==
// argmax first-max tie rule. sC stride 20 -> write banks 5*lane mod 32
// (2-way, free), read 8 distinct dwords broadcast (free).
// ---------------------------------------------------------------------------
__global__ __launch_bounds__(512, 2) void mega_kernel(
    const float* __restrict__ I,
    const float* __restrict__ T,
    const int* __restrict__ dims,
    const u16* __restrict__ Lbf,
    float* __restrict__ out)
{
    __shared__ float sI[2][16 * D_DIM];     // 64 KB: [buf][16 rows][512]
    __shared__ float sT[C_DIM * NODES_];    // 3.75 KB
    __shared__ u8    sC[2][C_DIM * 20];     // 2.5 KB: [buf][cls]{20}[row 0..15]

    const int tid  = threadIdx.x;
    const int lane = tid & 63;              // class c in codes phase
    const int wv   = tid >> 6;              // 0..7 = col-tile index
    const int rowBase = blockIdx.x * ROWS_B;

    // per-lane dim indices: one coalesced int4 (1 KB, L2-hot)
    const int4 dml = ((const int4*)dims)[lane];

    // ---- B preload: this wave's 32 fragments (128 VGPR), one-shot L2 ----
    uint4 Breg[32];
    #pragma unroll
    for (int ch = 0; ch < 32; ++ch)
        Breg[ch] = *(const uint4*)(Lbf + ((size_t)(wv * 32 + ch) * 64 + lane) * 8);

    auto issue = [&](int t) {   // stage subtile t's rows 2wv,2wv+1 (4 KB)
        const float* src = I + (size_t)(rowBase + t * 16 + wv * 2) * D_DIM;
        float* dst = &sI[t & 1][wv * 2 * D_DIM];
        #pragma unroll
        for (int i = 0; i < 4; ++i)
            gload_lds16(src + i * 256 + lane * 4, dst + i * 256);
    };

    const float* tc = sT + lane * NODES_;

    auto descend_write = [&](int t) {       // codes for rows 2wv,2wv+1, lane=cls
        u32 pk = 0;
        #pragma unroll
        for (int rr = 0; rr < 2; ++rr) {
            const float* v = &sI[t & 1][(wv * 2 + rr) * D_DIM];
            float x0 = v[dml.x], x1 = v[dml.y], x2 = v[dml.z], x3 = v[dml.w];
            int node = 0, k = 0;
            int b0 = (x0 - tc[0] > 0.0f) ? 1 : 0;
            k = b0; node = 1 + b0;
            int b1 = (x1 - tc[node] > 0.0f) ? 1 : 0;
            k = (k << 1) | b1; node = (node << 1) + 1 + b1;
            int b2 = (x2 - tc[node] > 0.0f) ? 1 : 0;
            k = (k << 1) | b2; node = (node << 1) + 1 + b2;
            int b3 = (x3 - tc[node] > 0.0f) ? 1 : 0;
            k = (k << 1) | b3;
            pk |= (u32)k << (8 * rr);
        }
        // one aligned u16 write: rows 2wv (lo byte), 2wv+1 (hi byte)
        *(u16*)(&sC[t & 1][lane * 20 + wv * 2]) = (u16)pk;
    };

    const int l15     = lane & 15;
    const int clsLane = (lane >> 5) & 1;        // which class of the k-chunk
    const int kb      = ((lane >> 4) & 1) * 8;  // k-offset within the class

    auto gemm_store = [&](int t) {
        f32x4 acc = {0.f, 0.f, 0.f, 0.f};
        const u8* cb = &sC[t & 1][0];
        #pragma unroll
        for (int ch = 0; ch < 32; ++ch) {
            const int cls = ch * 2 + clsLane;
            u32 cd = cb[cls * 20 + l15];        // code of (cls, row l15)
            u32 tt = cd - (u32)kb;              // one-hot slot if 0..7
            u64 sv = 0x3F80ull << ((tt & 3) * 16);
            union { u64 d[2]; short8v v; } a;
            a.d[0] = (tt < 4) ? sv : 0ull;
            a.d[1] = (tt >= 4 && tt < 8) ? sv : 0ull;
            union { uint4 u; short8v v; } b;
            b.u = Breg[ch];
            acc = __builtin_amdgcn_mfma_f32_16x16x32_bf16(a.v, b.v, acc, 0, 0, 0);
        }
        // D row = (lane>>4)*4 + j, col = lane&15 within (subtile t, ct wv)
        int r0 = rowBase + t * 16 + ((lane >> 4) << 2);
        float* o = out + (size_t)r0 * M_DIM + wv * 16 + l15;
        o[0 * M_DIM] = acc[0];
        o[1 * M_DIM] = acc[1];
        o[2 * M_DIM] = acc[2];
        o[3 * M_DIM] = acc[3];
    };

    // ---- prologue: stages 0,1 + B + sT all drained at one syncthreads ----
    issue(0); issue(1);
    for (int j = tid; j < C_DIM * NODES_; j += 512) sT[j] = T[j];
    __syncthreads();                // vmcnt 0: B, stage 0/1, dml, sT resident
    descend_write(0);
    lds_barrier();                  // sC[0] visible to all waves

    // ---- steady pipeline ----
    for (int t = 0; t < NSUB - 1; ++t) {
        gemm_store(t);              // reg/LDS gemm + 4 stores (overlap HBM)
        if (t < NSUB - 2) {
            issue(t + 2);           // into sI[t&1] (own rows, consumed at descend(t))
            WAIT_VM(4);             // drain stores(t)+stage(t+1); keep stage(t+2)
        } else {
            WAIT_VM(0);             // last descend: drain stage(7) fully
        }
        descend_write(t + 1);
        lds_barrier();              // raw: stage(t+2) stays in flight
    }
    gemm_store(NSUB - 1);
}

extern "C" void kernel_launch(void* const* d_in, const int* in_sizes, int n_in,
                              void* d_out, int out_size, void* d_ws, size_t ws_size,
                              hipStream_t stream) {
    // inputs: I(0) T(1) L(2) S(3) B(4) dims(5) temp(6) — fp32, dims int32
    const float* I    = (const float*)d_in[0];
    const float* T    = (const float*)d_in[1];
    const float* L    = (const float*)d_in[2];
    const int*   dims = (const int*)d_in[5];

    u16* Lbf = (u16*)d_ws;                      // 256 KB, fragment-ordered

    hipLaunchKernelGGL(build_lbf, dim3(64), dim3(256), 0, stream, L, Lbf);
    hipLaunchKernelGGL(mega_kernel, dim3(N_TOTAL / ROWS_B), dim3(512), 0, stream,
                       I, T, dims, Lbf, (float*)d_out);
}

// Round 10
// 126.712 us; speedup vs baseline: 1.0177x; 1.0177x over previous
//
#include <hip/hip_runtime.h>

#define N_TOTAL 32768
#define D_DIM   512
#define C_DIM   64
#define M_DIM   128
#define NODES_  15
#define ROWS_B  128         // rows per block -> grid = 256
#define NCHUNK  8           // codes chunks of 16 rows

typedef unsigned short u16;
typedef unsigned int   u32;
typedef unsigned long long u64;
typedef unsigned char  u8;
typedef float  f32x4   __attribute__((ext_vector_type(4)));
typedef short  short8v __attribute__((ext_vector_type(8)));

#define WAIT_VM(N) asm volatile("s_waitcnt vmcnt(" #N ")" ::: "memory")

__device__ __forceinline__ u32 f2bf_bits(float f) {
    u32 u = __float_as_uint(f);
    return (u + 0x7FFFu + ((u >> 16) & 1u)) >> 16;   // RNE
}

// coalesced global -> LDS direct copy, 16 B/lane (wave-uniform LDS base)
__device__ __forceinline__ void gload_lds16(const float* g, float* l) {
    __builtin_amdgcn_global_load_lds(
        (const __attribute__((address_space(1))) void*)g,
        (__attribute__((address_space(3))) void*)l, 16, 0, 0);
}

// ---------------------------------------------------------------------------
// Kernel 1 (unchanged, r4-verified): Lbf = L in MFMA-B-fragment order, bf16.
// Fragment (ct, ch): lane holds B[k][n], n = ct*16 + (lane&15),
// k = ch*32 + (lane>>4)*8 + i. Layout [ct][ch][lane][8]. 256 KB, L2-resident.
// ---------------------------------------------------------------------------
__global__ __launch_bounds__(256) void build_lbf(
    const float* __restrict__ L, u16* __restrict__ Lbf)
{
    int idx  = blockIdx.x * 256 + threadIdx.x;   // 16384 threads = 64 blocks
    int lane = idx & 63;
    int ch   = (idx >> 6) & 31;
    int ct   = idx >> 11;                        // 0..7
    int m  = ct * 16 + (lane & 15);
    int k0 = ch * 32 + ((lane >> 4) * 8);
    const float* src = L + (size_t)m * 1024 + k0;
    float4 a = *(const float4*)(src);
    float4 b = *(const float4*)(src + 4);
    u32 w0 = f2bf_bits(a.x) | (f2bf_bits(a.y) << 16);
    u32 w1 = f2bf_bits(a.z) | (f2bf_bits(a.w) << 16);
    u32 w2 = f2bf_bits(b.x) | (f2bf_bits(b.y) << 16);
    u32 w3 = f2bf_bits(b.z) | (f2bf_bits(b.w) << 16);
    *(uint4*)(Lbf + (size_t)idx * 8) = make_uint4(w0, w1, w2, w3);
}

// ---------------------------------------------------------------------------
// Kernel 2 (megakernel, simple 2-phase like r6-best, retiled 128 rows):
// 8 waves. Codes phase: 8 chunks of 16 rows (wave owns rows 2wv,2wv+1 of
// each chunk), double-buffered per-wave sI + counted WAIT_VM(4) 2-deep
// prefetch (r6-verified). Codes -> sC[cls][128] u8 in LDS.
// Gemm phase: wave = col-tile ct=wv. for ch: ONE B-frag L2 load (coalesced
// 1 KB, Lbf layout) feeds EIGHT MFMAs (rt=0..7) -> B off the critical path,
// B-traffic 64 MB total. A synthesized one-hot from sC (r4-verified
// formulas). C/D: col=lane&15, row=(lane>>4)*4+j (m89). h==0 -> bit 0 ==
// argmax first-max tie rule.
// sC stride 132: write banks 33*cls mod 32 = 2-way (free); read 8 banks
// broadcast (free). LDS = 64 + 3.75 + 8.25 = 76 KB.
// ---------------------------------------------------------------------------
__global__ __launch_bounds__(512, 2) void mega_kernel(
    const float* __restrict__ I,
    const float* __restrict__ T,
    const int* __restrict__ dims,
    const u16* __restrict__ Lbf,
    float* __restrict__ out)
{
    __shared__ float sI[2][16 * D_DIM];     // 64 KB: [buf][16 rows][512]
    __shared__ float sT[C_DIM * NODES_];    // 3.75 KB
    __shared__ u8    sC[C_DIM * 132];       // 8.25 KB: [cls]{132}[row 0..127]

    const int tid  = threadIdx.x;
    const int lane = tid & 63;              // class c in codes phase
    const int wv   = tid >> 6;              // 0..7
    const int rowBase = blockIdx.x * ROWS_B;

    // per-lane dim indices: one coalesced int4 (1 KB, L2-hot)
    const int4 dml = ((const int4*)dims)[lane];

    auto issue = [&](int t) {   // stage chunk t's rows 2wv,2wv+1 (4 KB, 4 loads)
        const float* src = I + (size_t)(rowBase + t * 16 + wv * 2) * D_DIM;
        float* dst = &sI[t & 1][wv * 2 * D_DIM];
        #pragma unroll
        for (int i = 0; i < 4; ++i)
            gload_lds16(src + i * 256 + lane * 4, dst + i * 256);
    };

    const float* tc = sT + lane * NODES_;

    auto descend_write = [&](int t) {       // codes rows 2wv,2wv+1, lane=cls
        u32 pk = 0;
        #pragma unroll
        for (int rr = 0; rr < 2; ++rr) {
            const float* v = &sI[t & 1][(wv * 2 + rr) * D_DIM];
            float x0 = v[dml.x], x1 = v[dml.y], x2 = v[dml.z], x3 = v[dml.w];
            int node = 0, k = 0;
            int b0 = (x0 - tc[0] > 0.0f) ? 1 : 0;
            k = b0; node = 1 + b0;
            int b1 = (x1 - tc[node] > 0.0f) ? 1 : 0;
            k = (k << 1) | b1; node = (node << 1) + 1 + b1;
            int b2 = (x2 - tc[node] > 0.0f) ? 1 : 0;
            k = (k << 1) | b2; node = (node << 1) + 1 + b2;
            int b3 = (x3 - tc[node] > 0.0f) ? 1 : 0;
            k = (k << 1) | b3;
            pk |= (u32)k << (8 * rr);
        }
        // one aligned u16 write: rows t*16+2wv (lo), +1 (hi); 2-way banks
        *(u16*)(sC + lane * 132 + t * 16 + wv * 2) = (u16)pk;
    };

    // ---- codes phase: r6-verified 2-deep counted-vmcnt pipeline ----
    issue(0); issue(1);
    for (int j = tid; j < C_DIM * NODES_; j += 512) sT[j] = T[j];
    __syncthreads();                // sT + chunks 0,1 + dml resident
    descend_write(0); issue(2);     // 4 in flight (c2)
    descend_write(1); issue(3);     // 8 (c2,c3)
    WAIT_VM(4); descend_write(2); issue(4);   // c2 done; 8 (c3,c4)
    WAIT_VM(4); descend_write(3); issue(5);
    WAIT_VM(4); descend_write(4); issue(6);
    WAIT_VM(4); descend_write(5); issue(7);
    WAIT_VM(4); descend_write(6);
    WAIT_VM(0); descend_write(7);
    __syncthreads();                // sC complete, all waves

    // ---- gemm phase: 1 B-load -> 8 MFMAs; acc[8] = 32 VGPR ----
    const int l15     = lane & 15;
    const int clsLane = (lane >> 5) & 1;        // which class of the k-chunk
    const int kb      = ((lane >> 4) & 1) * 8;  // k-offset within the class

    f32x4 acc[8] = {};
    const u16* lbW = Lbf + ((size_t)wv * 32 * 64 + lane) * 8;   // ct = wv

    #pragma unroll 4
    for (int ch = 0; ch < 32; ++ch) {
        union { uint4 u; short8v v; } b;
        b.u = *(const uint4*)(lbW + (size_t)ch * 64 * 8);
        const int cls = ch * 2 + clsLane;
        const u8* cb = sC + cls * 132;
        #pragma unroll
        for (int rt = 0; rt < 8; ++rt) {
            u32 cd = cb[rt * 16 + l15];         // code (cls, row rt*16+l15)
            u32 tt = cd - (u32)kb;              // one-hot slot if 0..7
            u64 sv = 0x3F80ull << ((tt & 3) * 16);
            union { u64 d[2]; short8v v; } a;
            a.d[0] = (tt < 4) ? sv : 0ull;
            a.d[1] = (tt >= 4 && tt < 8) ? sv : 0ull;
            acc[rt] = __builtin_amdgcn_mfma_f32_16x16x32_bf16(
                          a.v, b.v, acc[rt], 0, 0, 0);
        }
    }

    // ---- epilogue: D row = (lane>>4)*4 + j, col = lane&15 ----
    #pragma unroll
    for (int rt = 0; rt < 8; ++rt) {
        int r0 = rowBase + rt * 16 + ((lane >> 4) << 2);
        float* o = out + (size_t)r0 * M_DIM + wv * 16 + l15;
        o[0 * M_DIM] = acc[rt][0];
        o[1 * M_DIM] = acc[rt][1];
        o[2 * M_DIM] = acc[rt][2];
        o[3 * M_DIM] = acc[rt][3];
    }
}

extern "C" void kernel_launch(void* const* d_in, const int* in_sizes, int n_in,
                              void* d_out, int out_size, void* d_ws, size_t ws_size,
                              hipStream_t stream) {
    // inputs: I(0) T(1) L(2) S(3) B(4) dims(5) temp(6) — fp32, dims int32
    const float* I    = (const float*)d_in[0];
    const float* T    = (const float*)d_in[1];
    const float* L    = (const float*)d_in[2];
    const int*   dims = (const int*)d_in[5];

    u16* Lbf = (u16*)d_ws;                      // 256 KB, fragment-ordered

    hipLaunchKernelGGL(build_lbf, dim3(64), dim3(256), 0, stream, L, Lbf);
    hipLaunchKernelGGL(mega_kernel, dim3(N_TOTAL / ROWS_B), dim3(512), 0, stream,
                       I, T, dims, Lbf, (float*)d_out);
}